// Round 12
// baseline (140.762 us; speedup 1.0000x reference)
//
#include <hip/hip_runtime.h>
#include <hip/hip_fp16.h>
#include <math.h>

#define CC 64
#define KK 16
#define NNODES 15
#define DD 512      // input feature dim
#define MM 512      // output dim
#define NN 16384    // rows
#define KG 1024     // GEMM contraction dim = C*K

#define BM 128      // m-tile per block
#define BJ 128      // j-tile per block
#define BK 32       // k per step = 2 subspaces
#define LDA 40      // sA row stride in halves (80B: 16B-aligned, 2-way bank max)

typedef _Float16 half8_t __attribute__((ext_vector_type(8)));
typedef float float4_t __attribute__((ext_vector_type(4)));

// ---------------------------------------------------------------------------
// XLA/Eigen fast-tanh for f32 (bit-exact vs JAX's jnp.tanh lowering).
// Round 3/4/5 evidence: required to match the golden's argmax codes.
// ---------------------------------------------------------------------------
__device__ __forceinline__ float xla_tanhf(float x) {
    const float kMax = 7.90531110763549805f;
    bool tiny = fabsf(x) < 0.0004f;
    float xc = fminf(fmaxf(x, -kMax), kMax);
    float x2 = __fmul_rn(xc, xc);
    float p = __fmaf_rn(x2, -2.76076847742355e-16f, 2.00018790482477e-13f);
    p = __fmaf_rn(x2, p, -8.60467152213735e-11f);
    p = __fmaf_rn(x2, p, 5.12229709037114e-08f);
    p = __fmaf_rn(x2, p, 1.48572235717979e-05f);
    p = __fmaf_rn(x2, p, 6.37261928875436e-04f);
    p = __fmaf_rn(x2, p, 4.89352455891786e-03f);
    p = __fmul_rn(xc, p);
    float q = __fmaf_rn(x2, 1.19825839466702e-06f, 1.18534705686654e-04f);
    q = __fmaf_rn(x2, q, 2.26843463243900e-03f);
    q = __fmaf_rn(x2, q, 4.89352518554385e-03f);
    return tiny ? x : __fdiv_rn(p, q);
}

// ---------------------------------------------------------------------------
// Kernel 1: elementwise fp32 -> fp16 convert of L, LAYOUT PRESERVED (M, C*K).
// Native layout is k-contiguous per m-row == exactly the A-operand tiling.
// ---------------------------------------------------------------------------
__global__ __launch_bounds__(256) void convert_lut(const float* __restrict__ L,
                                                   __half* __restrict__ Lh) {
    int gid = blockIdx.x * 256 + threadIdx.x;   // over (M*KG)/4 = 131072
    float4 v = ((const float4*)L)[gid];
    __half2 a = __floats2half2_rn(v.x, v.y);
    __half2 b = __floats2half2_rn(v.z, v.w);
    ((__half2*)Lh)[2 * gid]     = a;
    ((__half2*)Lh)[2 * gid + 1] = b;
}

// ---------------------------------------------------------------------------
// Kernel 2: encode (bit-exact since round 5; conflict-free layouts r9-verified)
// ---------------------------------------------------------------------------
__global__ __launch_bounds__(256) void encode_kernel(const float* __restrict__ I,
                                                     const float* __restrict__ A,
                                                     const float* __restrict__ T,
                                                     unsigned char* __restrict__ idx) {
    __shared__ float sAT[32 * 64];     // [s*4+d][c]  transposed, conflict-free
    __shared__ float sTT[NNODES * 64]; // [i][c]      transposed, conflict-free
    const int tid = threadIdx.x;
    for (int g = tid; g < 32 * 64; g += 256)
        sAT[g] = A[((g & 63) << 5) + (g >> 6)];
    for (int g = tid; g < NNODES * 64; g += 256)
        sTT[g] = T[(g & 63) * NNODES + (g >> 6)];
    __syncthreads();

    int gid = blockIdx.x * 256 + tid;   // 0 .. N*C-1
    int j = gid >> 6;
    int c = gid & 63;

    const float* Ij = I + (size_t)j * DD + c * 8;
    float4 v0 = ((const float4*)Ij)[0];
    float4 v1 = ((const float4*)Ij)[1];
    float iv[8] = {v0.x, v0.y, v0.z, v0.w, v1.x, v1.y, v1.z, v1.w};

    float t[4] = {0.f, 0.f, 0.f, 0.f};
#pragma unroll
    for (int s = 0; s < 8; ++s) {
        float v = iv[s];
#pragma unroll
        for (int d = 0; d < 4; ++d)
            t[d] = __fmaf_rn(v, sAT[(s * 4 + d) * 64 + c], t[d]);
    }

    const int lvl[NNODES] = {0, 1, 1, 2, 2, 2, 2, 3, 3, 3, 3, 3, 3, 3, 3};
    float th[NNODES];
#pragma unroll
    for (int i = 0; i < NNODES; ++i) {
        float h = __fsub_rn(t[lvl[i]], sTT[i * 64 + c]);
        th[i] = xla_tanhf(h);
    }

    int best = 0;
    float bestv = -3.0e38f;
#pragma unroll
    for (int k = 0; k < KK; ++k) {
        int node = 0;
        float s = 0.f;
#pragma unroll
        for (int l = 0; l < 4; ++l) {
            int bit = (k >> (3 - l)) & 1;
            s = __fadd_rn(s, bit ? th[node] : -th[node]);
            node = 2 * node + 1 + bit;
        }
        if (s > bestv) { bestv = s; best = k; }   // strict >: first-max
    }
    idx[gid] = (unsigned char)best;               // coalesced byte stores
}

// ---------------------------------------------------------------------------
// Kernel 3: MFMA decode. out^T-tile D = A(Lh m x k) * B(one-hot k x j).
// 16x16x32 f16 MFMA. Verified layouts (m89/m91/m120):
//   A[m=lane&15][k=quad*8+i] (8 contiguous halves),
//   B[k=quad*8+i][n=lane&15],
//   D: col=lane&15, row=quad*4+reg.
// B built IN REGISTERS from codes (zero memory traffic); A staged to LDS
// double-buffered; codes staged once per block (8KB).
// ---------------------------------------------------------------------------
__global__ __launch_bounds__(256, 2) void gemm_decode(const __half* __restrict__ Lh,
                                                      const unsigned char* __restrict__ idx,
                                                      float* __restrict__ out) {
    __shared__ __half sA[2][BM * LDA];          // 2 x 10.0 KB
    __shared__ unsigned char sCode[CC * BJ];    // 8 KB, [c][j_local]

    const int tid = threadIdx.x;
    const int m0 = (blockIdx.x & 3) * BM;       // 4 m-tiles
    const int j0 = (blockIdx.x >> 2) * BJ;      // 128 j-tiles

    // ---- stage codes transposed: sCode[c][jl] = idx[(j0+jl)*64 + c]
    {
        const unsigned int* g = (const unsigned int*)(idx + (size_t)j0 * CC);
#pragma unroll
        for (int it = 0; it < 8; ++it) {
            int wi = it * 256 + tid;            // u32 index; byte base = wi*4
            unsigned int wv = g[wi];
            int jl = (wi * 4) >> 6;
            int c  = (wi * 4) & 63;             // c..c+3 stay in same jl
            sCode[(c + 0) * BJ + jl] = (unsigned char)(wv & 0xff);
            sCode[(c + 1) * BJ + jl] = (unsigned char)((wv >> 8) & 0xff);
            sCode[(c + 2) * BJ + jl] = (unsigned char)((wv >> 16) & 0xff);
            sCode[(c + 3) * BJ + jl] = (unsigned char)(wv >> 24);
        }
    }

    // ---- stage A tile for step 0: rows m0..m0+127, k 0..31 (64B/row)
    const int sr   = tid >> 1;        // row 0..127
    const int sseg = tid & 1;         // 16-half (32B) segment
    {
        const __half* gs = Lh + (size_t)(m0 + sr) * KG + sseg * 16;
        uint4 va = *(const uint4*)(gs);
        uint4 vb = *(const uint4*)(gs + 8);
        __half* ld = (__half*)sA[0] + sr * LDA + sseg * 16;
        *(uint4*)ld = va;
        *(uint4*)(ld + 8) = vb;
    }
    __syncthreads();

    const int lane = tid & 63;
    const int wv2  = tid >> 6;
    const int jw   = (wv2 & 1) * 64;
    const int mw   = (wv2 >> 1) * 64;
    const int l15  = lane & 15;
    const int quad = lane >> 4;
    const int kpar8 = (quad & 1) * 8;  // kk base within the 16-k half
    const int chalf = quad >> 1;       // which of the 2 c's this quad covers

    float4_t acc[4][4];
#pragma unroll
    for (int rf = 0; rf < 4; ++rf)
#pragma unroll
        for (int cf = 0; cf < 4; ++cf) acc[rf][cf] = (float4_t){0.f, 0.f, 0.f, 0.f};

    int buf = 0;
    for (int step = 0; step < 32; ++step) {
        uint4 pva, pvb;
        if (step < 31) {   // prefetch next A tile into regs
            const __half* gs = Lh + (size_t)(m0 + sr) * KG + (step + 1) * BK + sseg * 16;
            pva = *(const uint4*)(gs);
            pvb = *(const uint4*)(gs + 8);
        }

        // A fragments: 8 contiguous halves at row (mw+rf*16+l15), k-off quad*8
        half8_t a[4];
#pragma unroll
        for (int rf = 0; rf < 4; ++rf)
            a[rf] = *(const half8_t*)((const __half*)sA[buf] + (mw + rf * 16 + l15) * LDA + quad * 8);

        // B fragments: one-hot from code byte (11 VALU each, no memory)
        const int cbase = step * 2 + chalf;
        half8_t b[4];
#pragma unroll
        for (int cf = 0; cf < 4; ++cf) {
            int code = sCode[cbase * BJ + jw + cf * 16 + l15];
            int p = code - kpar8;                 // match position in 0..7, else miss
            int h = p >> 1;                       // arithmetic: negatives never match
            unsigned int sel = (p & 1) ? 0x3C000000u : 0x00003C00u;  // 1.0 f16 hi/lo
            uint4 bw;
            bw.x = (h == 0) ? sel : 0u;
            bw.y = (h == 1) ? sel : 0u;
            bw.z = (h == 2) ? sel : 0u;
            bw.w = (h == 3) ? sel : 0u;
            b[cf] = *(half8_t*)&bw;
        }

#pragma unroll
        for (int rf = 0; rf < 4; ++rf)
#pragma unroll
            for (int cf = 0; cf < 4; ++cf)
                acc[rf][cf] = __builtin_amdgcn_mfma_f32_16x16x32_f16(a[rf], b[cf], acc[rf][cf], 0, 0, 0);

        __syncthreads();
        if (step < 31) {
            __half* ld = (__half*)sA[buf ^ 1] + sr * LDA + sseg * 16;
            *(uint4*)ld = pva;
            *(uint4*)(ld + 8) = pvb;
            buf ^= 1;
        }
        __syncthreads();
    }

    // ---- epilogue: D row=quad*4+reg (m), col=l15 (j) -> float4 per lane
#pragma unroll
    for (int rf = 0; rf < 4; ++rf)
#pragma unroll
        for (int cf = 0; cf < 4; ++cf) {
            int j = j0 + jw + cf * 16 + l15;
            int m = m0 + mw + rf * 16 + quad * 4;
            *(float4*)(out + (size_t)j * MM + m) =
                make_float4(acc[rf][cf][0], acc[rf][cf][1], acc[rf][cf][2], acc[rf][cf][3]);
        }
}

// ---------------------------------------------------------------------------
extern "C" void kernel_launch(void* const* d_in, const int* in_sizes, int n_in,
                              void* d_out, int out_size, void* d_ws, size_t ws_size,
                              hipStream_t stream) {
    const float* I = (const float*)d_in[0];  // (N, D) fp32
    const float* A = (const float*)d_in[1];  // (C, 8, 4) fp32
    const float* T = (const float*)d_in[2];  // (C*15,) fp32
    const float* L = (const float*)d_in[3];  // (M, C, K) fp32
    // d_in[4] = S, d_in[5] = B: structural constants, hard-coded.

    __half* Lh = (__half*)d_ws;                                   // 1 MB fp16 LUT, native layout
    unsigned char* idx = (unsigned char*)d_ws + (1 << 20);        // 1 MB codes
    float* out = (float*)d_out;                                   // (N, M) fp32

    hipLaunchKernelGGL(convert_lut, dim3((MM * KG / 4) / 256), dim3(256), 0, stream, L, Lh);
    hipLaunchKernelGGL(encode_kernel, dim3((NN * CC) / 256), dim3(256), 0, stream, I, A, T, idx);
    hipLaunchKernelGGL(gemm_decode, dim3((NN / BJ) * (MM / BM)), dim3(256), 0, stream, Lh, idx, out);
}